// Round 3
// baseline (117.288 us; speedup 1.0000x reference)
//
#include <hip/hip_runtime.h>

// out[b,c,l] = sum_r x[b,r,l] * weight[idx[b,l], r, c] + bias[idx[b,l], c]
//   x:       (4, 256, 32, 32) fp32   flat (b*256 + r)*1024 + l
//   indexes: (4096,) int             j in [0,8)
//   weight:  (8, 256, 256) fp32      (j*256 + r)*256 + c
//   bias:    (8, 256) fp32
//   out:     (4, 256, 32, 32) fp32   (b*256 + c)*1024 + l
//
// Pipeline: bucket tokens by j (wave-aggregated) -> transpose x to (tok,r) ->
// 8 bucketed GEMMs (64 tok x 64 c tiles, K=256, double-buffered LDS,
// 4x4 register micro-tile) -> transpose (tok,c) to (b,c,l).

#define N_TOK   4096
#define R_MAX   256
#define C_DIM   256
#define N_J     8
#define MT      64      // tokens per GEMM block
#define NT      64      // channels per GEMM block
#define KC      32      // K chunk
#define LDA     68      // As row stride (floats): 16B-aligned, 4-way max on writes
#define LDB     68

__device__ float g_xt[N_TOK * R_MAX];        // 4 MB  (tok, r)
__device__ float g_outtmp[N_TOK * C_DIM];    // 4 MB  (tok, c)
__device__ int   g_perm[N_J * N_TOK];        // 8 oversized buckets
__device__ int   g_cnt[N_J];

// ---------------- Kernel A: bucket tokens by index (wave-aggregated) --------
__global__ __launch_bounds__(256) void bucket_kernel(const int* __restrict__ idx)
{
    __shared__ int cur_s[N_J];
    const int t = threadIdx.x;
    if (t < N_J) cur_s[t] = 0;
    __syncthreads();

    const int lane = t & 63;
    const unsigned long long below = (1ULL << lane) - 1ULL;

    #pragma unroll
    for (int i = 0; i < N_TOK / 256; ++i) {
        const int tok = i * 256 + t;
        const int j   = idx[tok];
        int pos = 0;
        #pragma unroll
        for (int jj = 0; jj < N_J; ++jj) {
            const unsigned long long m = __ballot(j == jj);
            if (j == jj) {
                const int leader = __ffsll(m) - 1;
                int base = 0;
                if (lane == leader) base = atomicAdd(&cur_s[jj], __popcll(m));
                base = __shfl(base, leader);
                pos = base + (int)__popcll(m & below);
            }
        }
        g_perm[j * N_TOK + pos] = tok;
    }
    __syncthreads();
    if (t < N_J) g_cnt[t] = cur_s[t];
}

// ---------------- Kernel B: x (b,r,l) -> xt (tok, r) ----------------
__global__ __launch_bounds__(256) void xpose_kernel(const float* __restrict__ x)
{
    __shared__ float T[64 * 65];
    const int t  = threadIdx.x;
    const int l0 = blockIdx.x * 64;
    const int r0 = blockIdx.y * 64;
    const int b  = blockIdx.z;

    const int lane_lo = t & 63;
    const int grp     = t >> 6;

    #pragma unroll
    for (int i = 0; i < 16; ++i) {
        const int rl = i * 4 + grp;
        const int ll = lane_lo;             // coalesced read over l
        T[rl * 65 + ll] = x[((b << 8) + r0 + rl) * 1024 + l0 + ll];
    }
    __syncthreads();
    #pragma unroll
    for (int i = 0; i < 16; ++i) {
        const int ll = i * 4 + grp;
        const int rl = lane_lo;             // coalesced write over r
        g_xt[((b << 10) + l0 + ll) * R_MAX + r0 + rl] = T[rl * 65 + ll];
    }
}

// ---------------- Kernel C: bucketed GEMM, double-buffered ----------------
// grid (4 c-tiles, 64 tok-tiles, 8 j), block 256.
// Out[64 tok x 64 c] = Xt[64 x 256] @ W_j[256 x 64] + bias_j
__global__ __launch_bounds__(256) void gemm_kernel(const float* __restrict__ weight,
                                                   const float* __restrict__ bias)
{
    const int j     = blockIdx.z;
    const int cb    = blockIdx.x * NT;
    const int cnt_j = g_cnt[j];
    const int start = blockIdx.y * MT;
    if (start >= cnt_j) return;
    const int rows = min(MT, cnt_j - start);

    __shared__ int   rowtok[MT];
    __shared__ float As[2][KC][LDA];
    __shared__ float Bs[2][KC][LDB];

    const int t = threadIdx.x;
    if (t < MT) rowtok[t] = g_perm[j * N_TOK + start + min(t, rows - 1)];
    __syncthreads();

    // Staging roles: A: 8 k-segments x 32 rows (x2); B: 16 k x 16 c-segs (x2)
    const int a_seg = t & 7;            // k = a_seg*4 .. +3
    const int a_row = t >> 3;           // 0..31, also +32
    const int b_k   = t >> 4;           // 0..15, also +16
    const int b_c   = (t & 15) * 4;

    const float* __restrict__ wj = weight + j * (R_MAX * C_DIM) + cb;
    const float* __restrict__ ap0 = g_xt + rowtok[a_row] * R_MAX + a_seg * 4;
    const float* __restrict__ ap1 = g_xt + rowtok[a_row + 32] * R_MAX + a_seg * 4;

    // Prologue: stage chunk 0 into buffer 0
    float4 ra0 = *(const float4*)(ap0);
    float4 ra1 = *(const float4*)(ap1);
    float4 rb0 = *(const float4*)(wj + b_k * C_DIM + b_c);
    float4 rb1 = *(const float4*)(wj + (b_k + 16) * C_DIM + b_c);

    As[0][a_seg * 4 + 0][a_row] = ra0.x;
    As[0][a_seg * 4 + 1][a_row] = ra0.y;
    As[0][a_seg * 4 + 2][a_row] = ra0.z;
    As[0][a_seg * 4 + 3][a_row] = ra0.w;
    As[0][a_seg * 4 + 0][a_row + 32] = ra1.x;
    As[0][a_seg * 4 + 1][a_row + 32] = ra1.y;
    As[0][a_seg * 4 + 2][a_row + 32] = ra1.z;
    As[0][a_seg * 4 + 3][a_row + 32] = ra1.w;
    *(float4*)&Bs[0][b_k][b_c]      = rb0;
    *(float4*)&Bs[0][b_k + 16][b_c] = rb1;
    __syncthreads();

    const int tx = t & 15;              // 4 channels at tx*4
    const int ty = t >> 4;              // 4 tokens at ty*4

    float4 acc0 = {0.f, 0.f, 0.f, 0.f};
    float4 acc1 = {0.f, 0.f, 0.f, 0.f};
    float4 acc2 = {0.f, 0.f, 0.f, 0.f};
    float4 acc3 = {0.f, 0.f, 0.f, 0.f};

    int p = 0;
    for (int k0 = 0; k0 < R_MAX; k0 += KC) {
        const int kn = k0 + KC;
        if (kn < R_MAX) {               // prefetch next chunk into regs
            ra0 = *(const float4*)(ap0 + kn);
            ra1 = *(const float4*)(ap1 + kn);
            rb0 = *(const float4*)(wj + (kn + b_k) * C_DIM + b_c);
            rb1 = *(const float4*)(wj + (kn + b_k + 16) * C_DIM + b_c);
        }
        #pragma unroll
        for (int kk = 0; kk < KC; ++kk) {
            const float4 av = *(const float4*)&As[p][kk][ty * 4];
            const float4 bv = *(const float4*)&Bs[p][kk][tx * 4];
            acc0.x += av.x * bv.x; acc0.y += av.x * bv.y; acc0.z += av.x * bv.z; acc0.w += av.x * bv.w;
            acc1.x += av.y * bv.x; acc1.y += av.y * bv.y; acc1.z += av.y * bv.z; acc1.w += av.y * bv.w;
            acc2.x += av.z * bv.x; acc2.y += av.z * bv.y; acc2.z += av.z * bv.z; acc2.w += av.z * bv.w;
            acc3.x += av.w * bv.x; acc3.y += av.w * bv.y; acc3.z += av.w * bv.z; acc3.w += av.w * bv.w;
        }
        if (kn < R_MAX) {
            const int q = p ^ 1;
            As[q][a_seg * 4 + 0][a_row] = ra0.x;
            As[q][a_seg * 4 + 1][a_row] = ra0.y;
            As[q][a_seg * 4 + 2][a_row] = ra0.z;
            As[q][a_seg * 4 + 3][a_row] = ra0.w;
            As[q][a_seg * 4 + 0][a_row + 32] = ra1.x;
            As[q][a_seg * 4 + 1][a_row + 32] = ra1.y;
            As[q][a_seg * 4 + 2][a_row + 32] = ra1.z;
            As[q][a_seg * 4 + 3][a_row + 32] = ra1.w;
            *(float4*)&Bs[q][b_k][b_c]      = rb0;
            *(float4*)&Bs[q][b_k + 16][b_c] = rb1;
            __syncthreads();
            p = q;
        }
    }

    // Epilogue: + bias, store to (tok, c)
    const float4 bb = *(const float4*)(bias + j * C_DIM + cb + tx * 4);
    const int r0 = ty * 4;
    if (r0 + 0 < rows) {
        float4 o = {acc0.x + bb.x, acc0.y + bb.y, acc0.z + bb.z, acc0.w + bb.w};
        *(float4*)(g_outtmp + rowtok[r0 + 0] * C_DIM + cb + tx * 4) = o;
    }
    if (r0 + 1 < rows) {
        float4 o = {acc1.x + bb.x, acc1.y + bb.y, acc1.z + bb.z, acc1.w + bb.w};
        *(float4*)(g_outtmp + rowtok[r0 + 1] * C_DIM + cb + tx * 4) = o;
    }
    if (r0 + 2 < rows) {
        float4 o = {acc2.x + bb.x, acc2.y + bb.y, acc2.z + bb.z, acc2.w + bb.w};
        *(float4*)(g_outtmp + rowtok[r0 + 2] * C_DIM + cb + tx * 4) = o;
    }
    if (r0 + 3 < rows) {
        float4 o = {acc3.x + bb.x, acc3.y + bb.y, acc3.z + bb.z, acc3.w + bb.w};
        *(float4*)(g_outtmp + rowtok[r0 + 3] * C_DIM + cb + tx * 4) = o;
    }
}

// ---------------- Kernel D: outtmp (tok,c) -> out (b,c,l) ----------------
__global__ __launch_bounds__(256) void opose_kernel(float* __restrict__ out)
{
    __shared__ float T[64 * 65];
    const int t  = threadIdx.x;
    const int l0 = blockIdx.x * 64;
    const int c0 = blockIdx.y * 64;
    const int b  = blockIdx.z;

    const int lane_lo = t & 63;
    const int grp     = t >> 6;

    #pragma unroll
    for (int i = 0; i < 16; ++i) {
        const int ll = i * 4 + grp;
        const int cl = lane_lo;             // coalesced read over c
        T[ll * 65 + cl] = g_outtmp[((b << 10) + l0 + ll) * C_DIM + c0 + cl];
    }
    __syncthreads();
    #pragma unroll
    for (int i = 0; i < 16; ++i) {
        const int cl = i * 4 + grp;
        const int ll = lane_lo;             // coalesced write over l
        out[((b << 8) + c0 + cl) * 1024 + l0 + ll] = T[ll * 65 + cl];
    }
}

extern "C" void kernel_launch(void* const* d_in, const int* in_sizes, int n_in,
                              void* d_out, int out_size, void* d_ws, size_t ws_size,
                              hipStream_t stream)
{
    const float* x      = (const float*)d_in[0];
    const int*   idx    = (const int*)  d_in[1];
    const float* weight = (const float*)d_in[2];
    const float* bias   = (const float*)d_in[3];
    float*       out    = (float*)      d_out;

    bucket_kernel<<<1, 256, 0, stream>>>(idx);
    xpose_kernel<<<dim3(16, 4, 4), 256, 0, stream>>>(x);
    gemm_kernel<<<dim3(4, MT, N_J), 256, 0, stream>>>(weight, bias);
    opose_kernel<<<dim3(16, 4, 4), 256, 0, stream>>>(out);
}

// Round 4
// 115.364 us; speedup vs baseline: 1.0167x; 1.0167x over previous
//
#include <hip/hip_runtime.h>

// out[b,c,l] = sum_r x[b,r,l] * weight[idx[b,l], r, c] + bias[idx[b,l], c]
//   x:       (4, 256, 32, 32) fp32   flat (b*256 + r)*1024 + l
//   indexes: (4096,) int             j in [0,8)
//   weight:  (8, 256, 256) fp32      (j*256 + r)*256 + c
//   bias:    (8, 256) fp32
//   out:     (4, 256, 32, 32) fp32   (b*256 + c)*1024 + l
//
// Pipeline: bucket tokens by j + build COMPACT tile map -> transpose x to
// (tok,r) -> bucketed GEMM over exactly-the-work-tiles (64 tok x 64 c,
// K=256, double-buffered LDS, 4x4 register micro-tile) -> transpose
// (tok,c) to (b,c,l).
//
// R4 fix: previous grid launched 2048 blocks of which ~256 (the low
// (y*4+x) IDs, same residues mod 256 for every j) did work -> all active
// blocks round-robined onto ~32 CUs, 8-deep serialization (~40 us). The
// tile map makes every launched block a working block, spread over all CUs.

#define N_TOK   4096
#define R_MAX   256
#define C_DIM   256
#define N_J     8
#define MT      64      // tokens per GEMM block
#define NT      64      // channels per GEMM block
#define KC      32      // K chunk
#define LDA     68      // As row stride (floats)
#define LDB     68
#define MAXTILE 80      // >= 64 + 7 possible partial tiles

__device__ float g_xt[N_TOK * R_MAX];        // 4 MB  (tok, r)
__device__ float g_outtmp[N_TOK * C_DIM];    // 4 MB  (tok, c)
__device__ int   g_perm[N_J * N_TOK];        // 8 oversized buckets
__device__ int   g_cnt[N_J];
__device__ int   g_tile_j[MAXTILE];          // tile -> bucket id (-1 = none)
__device__ int   g_tile_start[MAXTILE];      // tile -> start row within bucket

// ---------------- Kernel A: bucket tokens + build tile map ----------------
__global__ __launch_bounds__(256) void bucket_kernel(const int* __restrict__ idx)
{
    __shared__ int cur_s[N_J];
    const int t = threadIdx.x;
    if (t < N_J) cur_s[t] = 0;
    __syncthreads();

    const int lane = t & 63;
    const unsigned long long below = (1ULL << lane) - 1ULL;

    #pragma unroll
    for (int i = 0; i < N_TOK / 256; ++i) {
        const int tok = i * 256 + t;
        const int j   = idx[tok];
        int pos = 0;
        #pragma unroll
        for (int jj = 0; jj < N_J; ++jj) {
            const unsigned long long m = __ballot(j == jj);
            if (j == jj) {
                const int leader = __ffsll(m) - 1;
                int base = 0;
                if (lane == leader) base = atomicAdd(&cur_s[jj], __popcll(m));
                base = __shfl(base, leader);
                pos = base + (int)__popcll(m & below);
            }
        }
        g_perm[j * N_TOK + pos] = tok;
    }
    __syncthreads();
    if (t < N_J) g_cnt[t] = cur_s[t];

    if (t == 0) {
        int v = 0;
        for (int j = 0; j < N_J; ++j) {
            const int cnt = cur_s[j];
            for (int s = 0; s < cnt; s += MT) {
                g_tile_j[v]     = j;
                g_tile_start[v] = s;
                ++v;
            }
        }
        for (int w = v; w < MAXTILE; ++w) g_tile_j[w] = -1;
    }
}

// ---------------- Kernel B: x (b,r,l) -> xt (tok, r) ----------------
__global__ __launch_bounds__(256) void xpose_kernel(const float* __restrict__ x)
{
    __shared__ float T[64 * 65];
    const int t  = threadIdx.x;
    const int l0 = blockIdx.x * 64;
    const int r0 = blockIdx.y * 64;
    const int b  = blockIdx.z;

    const int lane_lo = t & 63;
    const int grp     = t >> 6;

    #pragma unroll
    for (int i = 0; i < 16; ++i) {
        const int rl = i * 4 + grp;
        const int ll = lane_lo;             // coalesced read over l
        T[rl * 65 + ll] = x[((b << 8) + r0 + rl) * 1024 + l0 + ll];
    }
    __syncthreads();
    #pragma unroll
    for (int i = 0; i < 16; ++i) {
        const int ll = i * 4 + grp;
        const int rl = lane_lo;             // coalesced write over r
        g_xt[((b << 10) + l0 + ll) * R_MAX + r0 + rl] = T[rl * 65 + ll];
    }
}

// ---------------- Kernel C: bucketed GEMM over compact tile map ----------
// grid (4 c-tiles, 72 tiles), block 256.
__global__ __launch_bounds__(256) void gemm_kernel(const float* __restrict__ weight,
                                                   const float* __restrict__ bias)
{
    const int v = blockIdx.y;
    const int j = g_tile_j[v];
    if (j < 0) return;
    const int cb    = blockIdx.x * NT;
    const int start = g_tile_start[v];
    const int rows  = min(MT, g_cnt[j] - start);

    __shared__ int   rowtok[MT];
    __shared__ float As[2][KC][LDA];
    __shared__ float Bs[2][KC][LDB];

    const int t = threadIdx.x;
    if (t < MT) rowtok[t] = g_perm[j * N_TOK + start + min(t, rows - 1)];
    __syncthreads();

    // Staging roles: A: 8 k-segments x 32 rows (x2); B: 16 k x 16 c-segs (x2)
    const int a_seg = t & 7;            // k = a_seg*4 .. +3
    const int a_row = t >> 3;           // 0..31, also +32
    const int b_k   = t >> 4;           // 0..15, also +16
    const int b_c   = (t & 15) * 4;

    const float* __restrict__ wj  = weight + j * (R_MAX * C_DIM) + cb;
    const float* __restrict__ ap0 = g_xt + rowtok[a_row] * R_MAX + a_seg * 4;
    const float* __restrict__ ap1 = g_xt + rowtok[a_row + 32] * R_MAX + a_seg * 4;

    // Prologue: stage chunk 0 into buffer 0
    float4 ra0 = *(const float4*)(ap0);
    float4 ra1 = *(const float4*)(ap1);
    float4 rb0 = *(const float4*)(wj + b_k * C_DIM + b_c);
    float4 rb1 = *(const float4*)(wj + (b_k + 16) * C_DIM + b_c);

    As[0][a_seg * 4 + 0][a_row] = ra0.x;
    As[0][a_seg * 4 + 1][a_row] = ra0.y;
    As[0][a_seg * 4 + 2][a_row] = ra0.z;
    As[0][a_seg * 4 + 3][a_row] = ra0.w;
    As[0][a_seg * 4 + 0][a_row + 32] = ra1.x;
    As[0][a_seg * 4 + 1][a_row + 32] = ra1.y;
    As[0][a_seg * 4 + 2][a_row + 32] = ra1.z;
    As[0][a_seg * 4 + 3][a_row + 32] = ra1.w;
    *(float4*)&Bs[0][b_k][b_c]      = rb0;
    *(float4*)&Bs[0][b_k + 16][b_c] = rb1;
    __syncthreads();

    const int tx = t & 15;              // 4 channels at tx*4
    const int ty = t >> 4;              // 4 tokens at ty*4

    float4 acc0 = {0.f, 0.f, 0.f, 0.f};
    float4 acc1 = {0.f, 0.f, 0.f, 0.f};
    float4 acc2 = {0.f, 0.f, 0.f, 0.f};
    float4 acc3 = {0.f, 0.f, 0.f, 0.f};

    int p = 0;
    for (int k0 = 0; k0 < R_MAX; k0 += KC) {
        const int kn = k0 + KC;
        if (kn < R_MAX) {               // prefetch next chunk into regs
            ra0 = *(const float4*)(ap0 + kn);
            ra1 = *(const float4*)(ap1 + kn);
            rb0 = *(const float4*)(wj + (kn + b_k) * C_DIM + b_c);
            rb1 = *(const float4*)(wj + (kn + b_k + 16) * C_DIM + b_c);
        }
        #pragma unroll
        for (int kk = 0; kk < KC; ++kk) {
            const float4 av = *(const float4*)&As[p][kk][ty * 4];
            const float4 bv = *(const float4*)&Bs[p][kk][tx * 4];
            acc0.x += av.x * bv.x; acc0.y += av.x * bv.y; acc0.z += av.x * bv.z; acc0.w += av.x * bv.w;
            acc1.x += av.y * bv.x; acc1.y += av.y * bv.y; acc1.z += av.y * bv.z; acc1.w += av.y * bv.w;
            acc2.x += av.z * bv.x; acc2.y += av.z * bv.y; acc2.z += av.z * bv.z; acc2.w += av.z * bv.w;
            acc3.x += av.w * bv.x; acc3.y += av.w * bv.y; acc3.z += av.w * bv.z; acc3.w += av.w * bv.w;
        }
        if (kn < R_MAX) {
            const int q = p ^ 1;
            As[q][a_seg * 4 + 0][a_row] = ra0.x;
            As[q][a_seg * 4 + 1][a_row] = ra0.y;
            As[q][a_seg * 4 + 2][a_row] = ra0.z;
            As[q][a_seg * 4 + 3][a_row] = ra0.w;
            As[q][a_seg * 4 + 0][a_row + 32] = ra1.x;
            As[q][a_seg * 4 + 1][a_row + 32] = ra1.y;
            As[q][a_seg * 4 + 2][a_row + 32] = ra1.z;
            As[q][a_seg * 4 + 3][a_row + 32] = ra1.w;
            *(float4*)&Bs[q][b_k][b_c]      = rb0;
            *(float4*)&Bs[q][b_k + 16][b_c] = rb1;
            __syncthreads();
            p = q;
        }
    }

    // Epilogue: + bias, store to (tok, c)
    const float4 bb = *(const float4*)(bias + j * C_DIM + cb + tx * 4);
    const int r0 = ty * 4;
    if (r0 + 0 < rows) {
        float4 o = {acc0.x + bb.x, acc0.y + bb.y, acc0.z + bb.z, acc0.w + bb.w};
        *(float4*)(g_outtmp + rowtok[r0 + 0] * C_DIM + cb + tx * 4) = o;
    }
    if (r0 + 1 < rows) {
        float4 o = {acc1.x + bb.x, acc1.y + bb.y, acc1.z + bb.z, acc1.w + bb.w};
        *(float4*)(g_outtmp + rowtok[r0 + 1] * C_DIM + cb + tx * 4) = o;
    }
    if (r0 + 2 < rows) {
        float4 o = {acc2.x + bb.x, acc2.y + bb.y, acc2.z + bb.z, acc2.w + bb.w};
        *(float4*)(g_outtmp + rowtok[r0 + 2] * C_DIM + cb + tx * 4) = o;
    }
    if (r0 + 3 < rows) {
        float4 o = {acc3.x + bb.x, acc3.y + bb.y, acc3.z + bb.z, acc3.w + bb.w};
        *(float4*)(g_outtmp + rowtok[r0 + 3] * C_DIM + cb + tx * 4) = o;
    }
}

// ---------------- Kernel D: outtmp (tok,c) -> out (b,c,l) ----------------
__global__ __launch_bounds__(256) void opose_kernel(float* __restrict__ out)
{
    __shared__ float T[64 * 65];
    const int t  = threadIdx.x;
    const int l0 = blockIdx.x * 64;
    const int c0 = blockIdx.y * 64;
    const int b  = blockIdx.z;

    const int lane_lo = t & 63;
    const int grp     = t >> 6;

    #pragma unroll
    for (int i = 0; i < 16; ++i) {
        const int ll = i * 4 + grp;
        const int cl = lane_lo;             // coalesced read over c
        T[ll * 65 + cl] = g_outtmp[((b << 10) + l0 + ll) * C_DIM + c0 + cl];
    }
    __syncthreads();
    #pragma unroll
    for (int i = 0; i < 16; ++i) {
        const int cl = i * 4 + grp;
        const int ll = lane_lo;             // coalesced write over l
        out[((b << 8) + c0 + cl) * 1024 + l0 + ll] = T[ll * 65 + cl];
    }
}

extern "C" void kernel_launch(void* const* d_in, const int* in_sizes, int n_in,
                              void* d_out, int out_size, void* d_ws, size_t ws_size,
                              hipStream_t stream)
{
    const float* x      = (const float*)d_in[0];
    const int*   idx    = (const int*)  d_in[1];
    const float* weight = (const float*)d_in[2];
    const float* bias   = (const float*)d_in[3];
    float*       out    = (float*)      d_out;

    bucket_kernel<<<1, 256, 0, stream>>>(idx);
    xpose_kernel<<<dim3(16, 4, 4), 256, 0, stream>>>(x);
    gemm_kernel<<<dim3(4, MAXTILE - N_J, 1), 256, 0, stream>>>(weight, bias);
    opose_kernel<<<dim3(16, 4, 4), 256, 0, stream>>>(out);
}

// Round 5
// 92.823 us; speedup vs baseline: 1.2636x; 1.2428x over previous
//
#include <hip/hip_runtime.h>

// out[b,c,l] = sum_r x[b,r,l] * weight[idx[b,l], r, c] + bias[idx[b,l], c]
//   x:       (4, 256, 32, 32) fp32   flat (b*256 + r)*1024 + l
//   indexes: (4096,) int             j in [0,8)
//   weight:  (8, 256, 256) fp32      (j*256 + r)*256 + c
//   bias:    (8, 256) fp32
//   out:     (4, 256, 32, 32) fp32   (b*256 + c)*1024 + l
//
// Pipeline:
//   zero_kernel     — reset g_cnt (device globals persist across calls)
//   scatter_kernel  — 16 blocks: ballot-aggregated bucket scatter (parallel;
//                     replaces R4's single-block 100 us latency-chain bucket)
//   xpose_kernel    — x (b,r,l) -> g_xt (tok, r), LDS 64x64 tiles
//   gemm_kernel     — 64 tok x 64 c tiles, K=256, double-buffered LDS,
//                     4x4 register micro-tile; each block derives its
//                     (j, start) from g_cnt with an 8-step scan (no tile map)
//   opose_kernel    — g_outtmp (tok,c) -> out (b,c,l)

#define N_TOK   4096
#define R_MAX   256
#define C_DIM   256
#define N_J     8
#define MT      64      // tokens per GEMM block
#define NT      64      // channels per GEMM block
#define KC      32      // K chunk
#define LDA     68      // As row stride (floats)
#define LDB     68
#define NTILE_Y 72      // >= max tiles = 64 + 7

__device__ float g_xt[N_TOK * R_MAX];        // 4 MB  (tok, r)
__device__ float g_outtmp[N_TOK * C_DIM];    // 4 MB  (tok, c)
__device__ int   g_perm[N_J * N_TOK];        // 8 oversized buckets
__device__ int   g_cnt[N_J];

// ---------------- Kernel A0: zero the global counters ----------------
__global__ __launch_bounds__(64) void zero_kernel()
{
    if (threadIdx.x < N_J) g_cnt[threadIdx.x] = 0;
}

// ---------------- Kernel A1: parallel bucket scatter ----------------
// 16 blocks x 256 threads, one token per thread.
__global__ __launch_bounds__(256) void scatter_kernel(const int* __restrict__ idx)
{
    __shared__ int loc[N_J];     // block-local counts
    __shared__ int base[N_J];    // block's base offset within each global bucket

    const int t = threadIdx.x;
    if (t < N_J) loc[t] = 0;
    __syncthreads();

    const int tok  = blockIdx.x * 256 + t;
    const int j    = idx[tok];
    const int lane = t & 63;
    const unsigned long long below = (1ULL << lane) - 1ULL;

    int lpos = 0;
    #pragma unroll
    for (int jj = 0; jj < N_J; ++jj) {
        const unsigned long long m = __ballot(j == jj);
        if (j == jj) {
            const int leader = __ffsll(m) - 1;
            int b = 0;
            if (lane == leader) b = atomicAdd(&loc[jj], (int)__popcll(m));
            b = __shfl(b, leader);
            lpos = b + (int)__popcll(m & below);
        }
    }
    __syncthreads();
    if (t < N_J) base[t] = atomicAdd(&g_cnt[t], loc[t]);   // device-scope
    __syncthreads();

    g_perm[j * N_TOK + base[j] + lpos] = tok;
}

// ---------------- Kernel B: x (b,r,l) -> xt (tok, r) ----------------
__global__ __launch_bounds__(256) void xpose_kernel(const float* __restrict__ x)
{
    __shared__ float T[64 * 65];
    const int t  = threadIdx.x;
    const int l0 = blockIdx.x * 64;
    const int r0 = blockIdx.y * 64;
    const int b  = blockIdx.z;

    const int lane_lo = t & 63;
    const int grp     = t >> 6;

    #pragma unroll
    for (int i = 0; i < 16; ++i) {
        const int rl = i * 4 + grp;
        const int ll = lane_lo;             // coalesced read over l
        T[rl * 65 + ll] = x[((b << 8) + r0 + rl) * 1024 + l0 + ll];
    }
    __syncthreads();
    #pragma unroll
    for (int i = 0; i < 16; ++i) {
        const int ll = i * 4 + grp;
        const int rl = lane_lo;             // coalesced write over r
        g_xt[((b << 10) + l0 + ll) * R_MAX + r0 + rl] = T[rl * 65 + ll];
    }
}

// ---------------- Kernel C: bucketed GEMM ----------------
// grid (4 c-tiles, 72 tiles), block 256. Each block scans g_cnt to find its
// (j, start); blocks past the last tile exit (few, and spread round-robin).
__global__ __launch_bounds__(256) void gemm_kernel(const float* __restrict__ weight,
                                                   const float* __restrict__ bias)
{
    const int v = blockIdx.y;
    int j = -1, start = 0, total = 0;
    #pragma unroll
    for (int jj = 0; jj < N_J; ++jj) {
        const int cnt = g_cnt[jj];
        const int ntl = (cnt + MT - 1) >> 6;
        if (j < 0 && v < total + ntl) { j = jj; start = (v - total) << 6; }
        total += ntl;
    }
    if (j < 0) return;

    const int cb   = blockIdx.x * NT;
    const int rows = min(MT, g_cnt[j] - start);

    __shared__ int   rowtok[MT];
    __shared__ float As[2][KC][LDA];
    __shared__ float Bs[2][KC][LDB];

    const int t = threadIdx.x;
    if (t < MT) rowtok[t] = g_perm[j * N_TOK + start + min(t, rows - 1)];
    __syncthreads();

    // Staging roles: A: 8 k-segments x 32 rows (x2); B: 16 k x 16 c-segs (x2)
    const int a_seg = t & 7;            // k = a_seg*4 .. +3
    const int a_row = t >> 3;           // 0..31, also +32
    const int b_k   = t >> 4;           // 0..15, also +16
    const int b_c   = (t & 15) * 4;

    const float* __restrict__ wj  = weight + j * (R_MAX * C_DIM) + cb;
    const float* __restrict__ ap0 = g_xt + rowtok[a_row] * R_MAX + a_seg * 4;
    const float* __restrict__ ap1 = g_xt + rowtok[a_row + 32] * R_MAX + a_seg * 4;

    // Prologue: stage chunk 0 into buffer 0
    float4 ra0 = *(const float4*)(ap0);
    float4 ra1 = *(const float4*)(ap1);
    float4 rb0 = *(const float4*)(wj + b_k * C_DIM + b_c);
    float4 rb1 = *(const float4*)(wj + (b_k + 16) * C_DIM + b_c);

    As[0][a_seg * 4 + 0][a_row] = ra0.x;
    As[0][a_seg * 4 + 1][a_row] = ra0.y;
    As[0][a_seg * 4 + 2][a_row] = ra0.z;
    As[0][a_seg * 4 + 3][a_row] = ra0.w;
    As[0][a_seg * 4 + 0][a_row + 32] = ra1.x;
    As[0][a_seg * 4 + 1][a_row + 32] = ra1.y;
    As[0][a_seg * 4 + 2][a_row + 32] = ra1.z;
    As[0][a_seg * 4 + 3][a_row + 32] = ra1.w;
    *(float4*)&Bs[0][b_k][b_c]      = rb0;
    *(float4*)&Bs[0][b_k + 16][b_c] = rb1;
    __syncthreads();

    const int tx = t & 15;              // 4 channels at tx*4
    const int ty = t >> 4;              // 4 tokens at ty*4

    float4 acc0 = {0.f, 0.f, 0.f, 0.f};
    float4 acc1 = {0.f, 0.f, 0.f, 0.f};
    float4 acc2 = {0.f, 0.f, 0.f, 0.f};
    float4 acc3 = {0.f, 0.f, 0.f, 0.f};

    int p = 0;
    for (int k0 = 0; k0 < R_MAX; k0 += KC) {
        const int kn = k0 + KC;
        if (kn < R_MAX) {               // prefetch next chunk into regs
            ra0 = *(const float4*)(ap0 + kn);
            ra1 = *(const float4*)(ap1 + kn);
            rb0 = *(const float4*)(wj + (kn + b_k) * C_DIM + b_c);
            rb1 = *(const float4*)(wj + (kn + b_k + 16) * C_DIM + b_c);
        }
        #pragma unroll
        for (int kk = 0; kk < KC; ++kk) {
            const float4 av = *(const float4*)&As[p][kk][ty * 4];
            const float4 bv = *(const float4*)&Bs[p][kk][tx * 4];
            acc0.x += av.x * bv.x; acc0.y += av.x * bv.y; acc0.z += av.x * bv.z; acc0.w += av.x * bv.w;
            acc1.x += av.y * bv.x; acc1.y += av.y * bv.y; acc1.z += av.y * bv.z; acc1.w += av.y * bv.w;
            acc2.x += av.z * bv.x; acc2.y += av.z * bv.y; acc2.z += av.z * bv.z; acc2.w += av.z * bv.w;
            acc3.x += av.w * bv.x; acc3.y += av.w * bv.y; acc3.z += av.w * bv.z; acc3.w += av.w * bv.w;
        }
        if (kn < R_MAX) {
            const int q = p ^ 1;
            As[q][a_seg * 4 + 0][a_row] = ra0.x;
            As[q][a_seg * 4 + 1][a_row] = ra0.y;
            As[q][a_seg * 4 + 2][a_row] = ra0.z;
            As[q][a_seg * 4 + 3][a_row] = ra0.w;
            As[q][a_seg * 4 + 0][a_row + 32] = ra1.x;
            As[q][a_seg * 4 + 1][a_row + 32] = ra1.y;
            As[q][a_seg * 4 + 2][a_row + 32] = ra1.z;
            As[q][a_seg * 4 + 3][a_row + 32] = ra1.w;
            *(float4*)&Bs[q][b_k][b_c]      = rb0;
            *(float4*)&Bs[q][b_k + 16][b_c] = rb1;
            __syncthreads();
            p = q;
        }
    }

    // Epilogue: + bias, store to (tok, c)
    const float4 bb = *(const float4*)(bias + j * C_DIM + cb + tx * 4);
    const int r0 = ty * 4;
    if (r0 + 0 < rows) {
        float4 o = {acc0.x + bb.x, acc0.y + bb.y, acc0.z + bb.z, acc0.w + bb.w};
        *(float4*)(g_outtmp + rowtok[r0 + 0] * C_DIM + cb + tx * 4) = o;
    }
    if (r0 + 1 < rows) {
        float4 o = {acc1.x + bb.x, acc1.y + bb.y, acc1.z + bb.z, acc1.w + bb.w};
        *(float4*)(g_outtmp + rowtok[r0 + 1] * C_DIM + cb + tx * 4) = o;
    }
    if (r0 + 2 < rows) {
        float4 o = {acc2.x + bb.x, acc2.y + bb.y, acc2.z + bb.z, acc2.w + bb.w};
        *(float4*)(g_outtmp + rowtok[r0 + 2] * C_DIM + cb + tx * 4) = o;
    }
    if (r0 + 3 < rows) {
        float4 o = {acc3.x + bb.x, acc3.y + bb.y, acc3.z + bb.z, acc3.w + bb.w};
        *(float4*)(g_outtmp + rowtok[r0 + 3] * C_DIM + cb + tx * 4) = o;
    }
}

// ---------------- Kernel D: outtmp (tok,c) -> out (b,c,l) ----------------
__global__ __launch_bounds__(256) void opose_kernel(float* __restrict__ out)
{
    __shared__ float T[64 * 65];
    const int t  = threadIdx.x;
    const int l0 = blockIdx.x * 64;
    const int c0 = blockIdx.y * 64;
    const int b  = blockIdx.z;

    const int lane_lo = t & 63;
    const int grp     = t >> 6;

    #pragma unroll
    for (int i = 0; i < 16; ++i) {
        const int ll = i * 4 + grp;
        const int cl = lane_lo;             // coalesced read over c
        T[ll * 65 + cl] = g_outtmp[((b << 10) + l0 + ll) * C_DIM + c0 + cl];
    }
    __syncthreads();
    #pragma unroll
    for (int i = 0; i < 16; ++i) {
        const int cl = i * 4 + grp;
        const int ll = lane_lo;             // coalesced write over l
        out[((b << 8) + c0 + cl) * 1024 + l0 + ll] = T[ll * 65 + cl];
    }
}

extern "C" void kernel_launch(void* const* d_in, const int* in_sizes, int n_in,
                              void* d_out, int out_size, void* d_ws, size_t ws_size,
                              hipStream_t stream)
{
    const float* x      = (const float*)d_in[0];
    const int*   idx    = (const int*)  d_in[1];
    const float* weight = (const float*)d_in[2];
    const float* bias   = (const float*)d_in[3];
    float*       out    = (float*)      d_out;

    zero_kernel<<<1, 64, 0, stream>>>();
    scatter_kernel<<<N_TOK / 256, 256, 0, stream>>>(idx);
    xpose_kernel<<<dim3(16, 4, 4), 256, 0, stream>>>(x);
    gemm_kernel<<<dim3(4, NTILE_Y, 1), 256, 0, stream>>>(weight, bias);
    opose_kernel<<<dim3(16, 4, 4), 256, 0, stream>>>(out);
}